// Round 1
// 700.948 us; speedup vs baseline: 1.0803x; 1.0803x over previous
//
#include <hip/hip_runtime.h>
#include <hip/hip_bf16.h>
#include <math.h>

// ---------------------------------------------------------------------------
// WindowAttention (self + mutual), MI355X / gfx950.
// R5: load-latency attack. rpbg stored permuted so softmax bias is one bf16x8
// load per (h,r); mask hoisted to registers once per group (head-invariant)
// and injected as the QK^T MFMA C-operand; QKV projection weight loads
// explicitly double-buffered (bA/bB, parity-static) to keep 6 loads in
// flight under the MFMAs. Structure/LDS layout otherwise unchanged from R4.
// ---------------------------------------------------------------------------

#define SCALE_F 0.17677669529663687f   // 32^-0.5
#define LOG2E_F 1.4426950408889634f

// ws layout (bytes)
#define WS_WQKV_T   0u        // [576][192] bf16 (W^T: [col][k]; Q-cols ×SCALE×LOG2E)
#define WS_WQKVM_T  221184u   // [576][192] bf16
#define WS_WPROJ_T  442368u   // [192 n][384 k] bf16
#define WS_RPBG     589824u   // [6][128][128] bf16, PERMUTED [h][i][l16*8+ct], ×LOG2E
#define WS_NEEDED   786432u

typedef __bf16 bf16x8 __attribute__((ext_vector_type(8)));
typedef __bf16 bf16x4 __attribute__((ext_vector_type(4)));
typedef float  f32x4  __attribute__((ext_vector_type(4)));

#define MFMA(a, b, c) __builtin_amdgcn_mfma_f32_16x16x32_bf16((a), (b), (c), 0, 0, 0)

#if __has_builtin(__builtin_amdgcn_exp2f)
#define EXP2(x) __builtin_amdgcn_exp2f(x)
#else
#define EXP2(x) exp2f(x)
#endif
#if __has_builtin(__builtin_amdgcn_rcpf)
#define RCP(x) __builtin_amdgcn_rcpf(x)
#else
#define RCP(x) (1.0f / (x))
#endif

// ---------------------------------------------------------------------------
__global__ void prep_kernel(const float* __restrict__ w_qkv,
                            const float* __restrict__ w_qkvm,
                            const float* __restrict__ w_proj,
                            const float* __restrict__ rpb_table,
                            const int*   __restrict__ rel_idx,
                            char* __restrict__ ws) {
    int idx = blockIdx.x * 256 + threadIdx.x;
    if (idx < 110592) {                       // wqkv_t / wqkvm_t: [col][k]
        int col = idx / 192, k = idx - col * 192;
        float sc = (col < 192) ? SCALE_F * LOG2E_F : 1.0f;  // Q pre-scale (exp2 form)
        ((__bf16*)(ws + WS_WQKV_T))[idx]  = (__bf16)(w_qkv[k * 576 + col] * sc);
        ((__bf16*)(ws + WS_WQKVM_T))[idx] = (__bf16)(w_qkvm[k * 576 + col] * sc);
    } else if (idx < 184320) {                // wproj_t: [n][k]
        int o = idx - 110592;
        int n = o / 384, k = o - n * 384;
        ((__bf16*)(ws + WS_WPROJ_T))[o] = (__bf16)w_proj[k * 192 + n];
    } else if (idx < 282624) {                // rpbg permuted: [h][i][l16*8+ct]
        int o = idx - 184320;
        int h = o / 16384, r2 = o - h * 16384;
        int i = r2 >> 7, c = r2 & 127;
        int l16 = c >> 3, ct = c & 7;
        int j = l16 + ct * 16;                // original column index
        ((__bf16*)(ws + WS_RPBG))[o] =
            (__bf16)(rpb_table[rel_idx[i * 128 + j] * 6 + h] * LOG2E_F);
    }
}

// ---------------------------------------------------------------------------
// Block = (window, branch). 512 threads = 8 waves; wave w owns query rows
// [16w, 16w+16). MFMA 16x16x32 bf16 layouts (HW-verified):
//   A[m = lane&15][k = quad*8 + j]; B[k = quad*8 + j][n = lane&15]
//   D: col = lane&15, row = quad*4 + reg
// LDS (79,360 B -> 2 blocks/CU):
//   kh3  [128][104] @ 0       K for 3 heads (local 96 cols + pad)
//   vt3  [ 96][136] @ 26624   V^T for 3 heads [dim][token]
//   qs   [8][16][104] @ 52736 wave-private Q staging / P staging
//   outs [128][200] @ 0       output transpose buffer (overlays kh3+vt3,
//                             used only after the final group barrier)
__global__ __launch_bounds__(512, 4)
void attn_kernel(const float* __restrict__ x,
                 const float* __restrict__ mask,
                 const float* __restrict__ pos_bias,
                 const char*  __restrict__ ws,
                 __bf16* __restrict__ concat) {
    __shared__ alignas(16) char smem[79360];
    __bf16 (*kh3)[104]     = (__bf16(*)[104])smem;
    __bf16 (*vt3)[136]     = (__bf16(*)[136])(smem + 26624);
    __bf16 (*qs)[16][104]  = (__bf16(*)[16][104])(smem + 52736);
    __bf16 (*outs)[200]    = (__bf16(*)[200])smem;

    const int b      = blockIdx.x >> 1;
    const int branch = blockIdx.x & 1;
    const int wm     = b & 63;
    const int tid    = threadIdx.x;
    const int wave   = tid >> 6;
    const int lane   = tid & 63;
    const int quad   = lane >> 4;
    const int l16    = lane & 15;
    const int mrow   = wave * 16;

    const __bf16* wt   = (const __bf16*)(ws + (branch ? WS_WQKVM_T : WS_WQKV_T));
    const __bf16* rpbg = (const __bf16*)(ws + WS_RPBG);

    // ---- x rows for this wave -> A-fragments in registers (reused 6x) ----
    bf16x8 afrag[6];
    {
        const float* xr = x + (size_t)b * 24576 + (mrow + l16) * 192;
        const float* pr = pos_bias + ((mrow + l16) & 63) * 192;
        #pragma unroll
        for (int ks = 0; ks < 6; ++ks) {
            const int k0 = ks * 32 + quad * 8;
            float4 v0 = *(const float4*)(xr + k0);
            float4 v1 = *(const float4*)(xr + k0 + 4);
            if (branch) {
                float4 p0 = *(const float4*)(pr + k0);
                float4 p1 = *(const float4*)(pr + k0 + 4);
                v0.x += p0.x; v0.y += p0.y; v0.z += p0.z; v0.w += p0.w;
                v1.x += p1.x; v1.y += p1.y; v1.z += p1.z; v1.w += p1.w;
            }
            bf16x8 f;
            f[0] = (__bf16)v0.x; f[1] = (__bf16)v0.y;
            f[2] = (__bf16)v0.z; f[3] = (__bf16)v0.w;
            f[4] = (__bf16)v1.x; f[5] = (__bf16)v1.y;
            f[6] = (__bf16)v1.z; f[7] = (__bf16)v1.w;
            afrag[ks] = f;
        }
    }

    // ---- double-buffered weight-fragment projection: acc[6] += x @ W^T ----
    auto runproj = [&](int rowbase, f32x4* acc) {
        const __bf16* wb = wt + (size_t)(rowbase + l16) * 192 + quad * 8;
        bf16x8 bA[6], bB[6];
        #pragma unroll
        for (int nt = 0; nt < 6; ++nt)
            bA[nt] = *(const bf16x8*)(wb + nt * 3072);
        #pragma unroll
        for (int ks = 0; ks < 6; ++ks) {
            if ((ks & 1) == 0) {
                if (ks < 5) {
                    #pragma unroll
                    for (int nt = 0; nt < 6; ++nt)
                        bB[nt] = *(const bf16x8*)(wb + (ks + 1) * 32 + nt * 3072);
                }
                #pragma unroll
                for (int nt = 0; nt < 6; ++nt)
                    acc[nt] = MFMA(afrag[ks], bA[nt], acc[nt]);
            } else {
                if (ks < 5) {
                    #pragma unroll
                    for (int nt = 0; nt < 6; ++nt)
                        bA[nt] = *(const bf16x8*)(wb + (ks + 1) * 32 + nt * 3072);
                }
                #pragma unroll
                for (int nt = 0; nt < 6; ++nt)
                    acc[nt] = MFMA(afrag[ks], bB[nt], acc[nt]);
            }
        }
    };

    unsigned ob[6][4];   // packed bf16 pair (col l16, col l16+16) per head per r

    #pragma unroll
    for (int g = 0; g < 2; ++g) {
        const int hc = g * 96;

        // ---- K (3 heads) -> kh3 [token][dim] ----
        {
            f32x4 acc[6] = {};
            runproj(192 + hc, acc);
            #pragma unroll
            for (int nt = 0; nt < 6; ++nt)
                #pragma unroll
                for (int r = 0; r < 4; ++r)
                    kh3[mrow + quad * 4 + r][nt * 16 + l16] = (__bf16)acc[nt][r];
        }
        // ---- V (3 heads) -> vt3 [dim][token], packed b64 writes ----
        {
            f32x4 acc[6] = {};
            runproj(384 + hc, acc);
            #pragma unroll
            for (int nt = 0; nt < 6; ++nt) {
                bf16x4 pv;
                #pragma unroll
                for (int r = 0; r < 4; ++r) pv[r] = (__bf16)acc[nt][r];
                *(bf16x4*)&vt3[nt * 16 + l16][mrow + quad * 4] = pv;
            }
        }
        // ---- Q (3 heads, pre-scaled) -> wave-private qs -> registers ----
        bf16x8 aq[3];
        {
            f32x4 acc[6] = {};
            runproj(hc, acc);
            #pragma unroll
            for (int nt = 0; nt < 6; ++nt)
                #pragma unroll
                for (int r = 0; r < 4; ++r)
                    qs[wave][quad * 4 + r][nt * 16 + l16] = (__bf16)acc[nt][r];
            #pragma unroll
            for (int hl = 0; hl < 3; ++hl)
                aq[hl] = *(const bf16x8*)&qs[wave][l16][hl * 32 + quad * 8];
        }
        __syncthreads();    // K/V visible; Q private in regs

        __bf16 (*spw)[104] = qs[wave];   // Q slot dead -> P staging

        if (branch == 0) {
            // mask is head-invariant: load once per group, pre-scaled, laid
            // out as the QK^T C-operand (D-frag: row=quad*4+r, col=ct*16+l16)
            f32x4 mkc[8];
            {
                const float* mp = mask + ((size_t)wm * 128 + mrow + quad * 4) * 128 + l16;
                #pragma unroll
                for (int ct = 0; ct < 8; ++ct)
                    #pragma unroll
                    for (int r = 0; r < 4; ++r)
                        mkc[ct][r] = mp[r * 128 + ct * 16] * LOG2E_F;
            }
            #pragma unroll
            for (int hl = 0; hl < 3; ++hl) {
                const int h = g * 3 + hl;
                f32x4 s[8];
                #pragma unroll
                for (int ct = 0; ct < 8; ++ct) {
                    bf16x8 bk = *(const bf16x8*)&kh3[ct * 16 + l16][hl * 32 + quad * 8];
                    s[ct] = MFMA(aq[hl], bk, mkc[ct]);   // mask folded into C
                }
                // rpb: one bf16x8 per r (permuted table), coalesced
                bf16x8 rv[4];
                {
                    const __bf16* rbase = rpbg
                        + ((size_t)(h * 128 + mrow + quad * 4) << 7) + l16 * 8;
                    #pragma unroll
                    for (int r = 0; r < 4; ++r)
                        rv[r] = *(const bf16x8*)(rbase + r * 128);
                }
                float rl[4];
                #pragma unroll
                for (int r = 0; r < 4; ++r) {
                    float sum = 0.f;
                    #pragma unroll
                    for (int ct = 0; ct < 8; ++ct) {
                        float p = EXP2(s[ct][r] + (float)rv[r][ct]);
                        s[ct][r] = p;
                        sum += p;
                    }
                    #pragma unroll
                    for (int off = 1; off < 16; off <<= 1)
                        sum += __shfl_xor(sum, off, 64);
                    rl[r] = RCP(sum);
                }
                // PV: two 64-key batches, one RAW stall each
                f32x4 o[2] = {};
                #pragma unroll
                for (int kb2 = 0; kb2 < 2; ++kb2) {
                    #pragma unroll
                    for (int ct = 0; ct < 4; ++ct)
                        #pragma unroll
                        for (int r = 0; r < 4; ++r)
                            spw[quad * 4 + r][ct * 16 + l16] = (__bf16)s[kb2 * 4 + ct][r];
                    #pragma unroll
                    for (int kb = 0; kb < 2; ++kb) {
                        const int k0l = kb * 32 + quad * 8;
                        bf16x8 p = *(const bf16x8*)&spw[l16][k0l];
                        #pragma unroll
                        for (int nt = 0; nt < 2; ++nt) {
                            bf16x8 bv = *(const bf16x8*)
                                &vt3[hl * 32 + nt * 16 + l16][kb2 * 64 + k0l];
                            o[nt] = MFMA(p, bv, o[nt]);
                        }
                    }
                }
                #pragma unroll
                for (int r = 0; r < 4; ++r) {
                    union { __bf16 hh[2]; unsigned u; } pk;
                    pk.hh[0] = (__bf16)(o[0][r] * rl[r]);
                    pk.hh[1] = (__bf16)(o[1][r] * rl[r]);
                    ob[h][r] = pk.u;
                }
            }
        } else {
            const int kbase = (mrow < 64) ? 64 : 0;
            f32x4 mkc[4];
            {
                const float* mp = mask
                    + ((size_t)wm * 128 + ((mrow + quad * 4) & 63)) * 128 + l16;
                #pragma unroll
                for (int ct = 0; ct < 4; ++ct)
                    #pragma unroll
                    for (int r = 0; r < 4; ++r)
                        mkc[ct][r] = mp[r * 128 + ct * 16] * LOG2E_F;
            }
            #pragma unroll
            for (int hl = 0; hl < 3; ++hl) {
                const int h = g * 3 + hl;
                f32x4 s[4];
                #pragma unroll
                for (int ct = 0; ct < 4; ++ct) {
                    bf16x8 bk = *(const bf16x8*)&kh3[kbase + ct * 16 + l16][hl * 32 + quad * 8];
                    s[ct] = MFMA(aq[hl], bk, mkc[ct]);   // mask folded into C
                }
                float rl[4];
                #pragma unroll
                for (int r = 0; r < 4; ++r) {
                    float sum = 0.f;
                    #pragma unroll
                    for (int ct = 0; ct < 4; ++ct) {
                        float p = EXP2(s[ct][r]);
                        s[ct][r] = p;
                        sum += p;
                    }
                    #pragma unroll
                    for (int off = 1; off < 16; off <<= 1)
                        sum += __shfl_xor(sum, off, 64);
                    rl[r] = RCP(sum);
                }
                #pragma unroll
                for (int ct = 0; ct < 4; ++ct)
                    #pragma unroll
                    for (int r = 0; r < 4; ++r)
                        spw[quad * 4 + r][ct * 16 + l16] = (__bf16)s[ct][r];
                f32x4 o[2] = {};
                #pragma unroll
                for (int kb = 0; kb < 2; ++kb) {
                    const int k0l = kb * 32 + quad * 8;
                    bf16x8 p = *(const bf16x8*)&spw[l16][k0l];
                    #pragma unroll
                    for (int nt = 0; nt < 2; ++nt) {
                        bf16x8 bv = *(const bf16x8*)
                            &vt3[hl * 32 + nt * 16 + l16][kbase + k0l];
                        o[nt] = MFMA(p, bv, o[nt]);
                    }
                }
                #pragma unroll
                for (int r = 0; r < 4; ++r) {
                    union { __bf16 hh[2]; unsigned u; } pk;
                    pk.hh[0] = (__bf16)(o[0][r] * rl[r]);
                    pk.hh[1] = (__bf16)(o[1][r] * rl[r]);
                    ob[h][r] = pk.u;
                }
            }
        }
        __syncthreads();    // kh3/vt3 readers done before next group / outs
    }

    // ---- output: regs -> LDS transpose -> coalesced uint4 global stores ----
    #pragma unroll
    for (int h = 0; h < 6; ++h)
        #pragma unroll
        for (int r = 0; r < 4; ++r) {
            const int i = mrow + quad * 4 + r;
            const int row = branch ? ((i + 64) & 127) : i;   // mutual token rotation
            union { unsigned u; __bf16 hh[2]; } pk;
            pk.u = ob[h][r];
            outs[row][h * 32 + l16]      = pk.hh[0];
            outs[row][h * 32 + 16 + l16] = pk.hh[1];
        }
    __syncthreads();
    {
        const int colofs = branch ? 0 : 192;
        #pragma unroll
        for (int i = 0; i < 6; ++i) {
            int f = tid + i * 512;            // 0..3071 (128 rows x 24 uint4)
            int row = f / 24;
            int c8 = (f - row * 24) * 8;
            *(uint4*)&concat[((size_t)b * 128 + row) * 384 + colofs + c8] =
                *(const uint4*)&outs[row][c8];
        }
    }
}

// ---------------------------------------------------------------------------
// out = concat @ w_proj + b_proj. 64 rows/block, 256 thr (4 waves x 16 rows),
// weights staged in four 96-K chunks (38.4 KB LDS -> 4 blocks/CU). A-frags
// hoisted before first barrier. concat aliases d_out: rows block-exclusive,
// reads complete (in-wave) before epilogue stores.
__global__ __launch_bounds__(256, 4)
void proj_kernel(const __bf16* __restrict__ concat,
                 const char* __restrict__ ws,
                 const float* __restrict__ b_proj,
                 float* __restrict__ out) {
    __shared__ alignas(16) __bf16 bw[192][100];
    const __bf16* wp = (const __bf16*)(ws + WS_WPROJ_T);
    const int tid  = threadIdx.x;
    const int wave = tid >> 6;
    const int lane = tid & 63;
    const int quad = lane >> 4;
    const int l16  = lane & 15;
    const int mrow = wave * 16;
    const size_t r0 = (size_t)blockIdx.x * 64;

    bf16x8 a[12];
    {
        const __bf16* arow = concat + (r0 + mrow + l16) * 384;
        #pragma unroll
        for (int ks = 0; ks < 12; ++ks)
            a[ks] = *(const bf16x8*)&arow[ks * 32 + quad * 8];
    }
    f32x4 acc[12] = {};
    for (int c = 0; c < 4; ++c) {
        if (c) __syncthreads();
        #pragma unroll
        for (int i = 0; i < 9; ++i) {
            int f = tid + i * 256;            // 0..2303 (192 rows x 12 uint4)
            int row = f / 12;
            int cc = (f - row * 12) * 8;
            *(uint4*)&bw[row][cc] = *(const uint4*)&wp[row * 384 + c * 96 + cc];
        }
        __syncthreads();
        #pragma unroll
        for (int k3 = 0; k3 < 3; ++k3) {
            const int k0 = k3 * 32 + quad * 8;
            bf16x8 af = a[c * 3 + k3];
            #pragma unroll
            for (int nt = 0; nt < 12; ++nt) {
                bf16x8 bb = *(const bf16x8*)&bw[nt * 16 + l16][k0];
                acc[nt] = MFMA(af, bb, acc[nt]);
            }
        }
    }
    #pragma unroll
    for (int nt = 0; nt < 12; ++nt) {
        const int cc = nt * 16 + l16;
        const float bias = b_proj[cc];
        #pragma unroll
        for (int r = 0; r < 4; ++r)
            out[(r0 + mrow + quad * 4 + r) * 192 + cc] = acc[nt][r] + bias;
    }
}

// ---------------------------------------------------------------------------
extern "C" void kernel_launch(void* const* d_in, const int* in_sizes, int n_in,
                              void* d_out, int out_size, void* d_ws, size_t ws_size,
                              hipStream_t stream) {
    const float* x       = (const float*)d_in[0];
    const float* mask    = (const float*)d_in[1];
    const float* w_qkv   = (const float*)d_in[2];
    const float* w_qkvm  = (const float*)d_in[3];
    const float* w_proj  = (const float*)d_in[4];
    const float* b_proj  = (const float*)d_in[5];
    const float* rpb     = (const float*)d_in[6];
    const float* pos_b   = (const float*)d_in[7];
    const int*   rel_idx = (const int*)d_in[8];

    if (ws_size < WS_NEEDED) return;

    char*   ws     = (char*)d_ws;
    __bf16* concat = (__bf16*)d_out;   // 131072*384 bf16 == out bytes, exact fit
    float*  out    = (float*)d_out;

    prep_kernel<<<1104, 256, 0, stream>>>(w_qkv, w_qkvm, w_proj, rpb, rel_idx, ws);
    attn_kernel<<<2048, 512, 0, stream>>>(x, mask, pos_b, ws, concat);
    proj_kernel<<<2048, 256, 0, stream>>>(concat, ws, b_proj, out);
}

// Round 2
// 509.155 us; speedup vs baseline: 1.4873x; 1.3767x over previous
//
#include <hip/hip_runtime.h>
#include <hip/hip_bf16.h>
#include <math.h>

// ---------------------------------------------------------------------------
// WindowAttention (self + mutual), MI355X / gfx950.
// R6: occupancy + L2-locality attack. Per-head pipeline cuts LDS 79.4KB ->
// 37.4KB (2 -> 4 blocks/CU, 32 waves/CU); branch0 softmax split into two
// 64-key halves (s4[4] live instead of s[8]) to hold ~64 VGPRs; XCD-bijective
// block swizzle (branch pairs + 8 mask windows per XCD L2); weight tables
// re-laid [ks][col][32] for fully-coalesced 1KB proj load batches; per-head
// output store via wave-private LDS transpose (outs overlay eliminated).
// ---------------------------------------------------------------------------

#define SCALE_F 0.17677669529663687f   // 32^-0.5
#define LOG2E_F 1.4426950408889634f

// ws layout (bytes)
#define WS_WQKV_T   0u        // [6 ks][576 col][32 k] bf16 (Q-cols ×SCALE×LOG2E)
#define WS_WQKVM_T  221184u   // [6 ks][576 col][32 k] bf16
#define WS_WPROJ_T  442368u   // [192 n][384 k] bf16
#define WS_RPBG     589824u   // [6][128][half*64 + l16*4 + j] bf16, ×LOG2E
#define WS_NEEDED   786432u

typedef __bf16 bf16x8 __attribute__((ext_vector_type(8)));
typedef __bf16 bf16x4 __attribute__((ext_vector_type(4)));
typedef float  f32x4  __attribute__((ext_vector_type(4)));

#define MFMA(a, b, c) __builtin_amdgcn_mfma_f32_16x16x32_bf16((a), (b), (c), 0, 0, 0)

#if __has_builtin(__builtin_amdgcn_exp2f)
#define EXP2(x) __builtin_amdgcn_exp2f(x)
#else
#define EXP2(x) exp2f(x)
#endif
#if __has_builtin(__builtin_amdgcn_rcpf)
#define RCP(x) __builtin_amdgcn_rcpf(x)
#else
#define RCP(x) (1.0f / (x))
#endif

// ---------------------------------------------------------------------------
__global__ void prep_kernel(const float* __restrict__ w_qkv,
                            const float* __restrict__ w_qkvm,
                            const float* __restrict__ w_proj,
                            const float* __restrict__ rpb_table,
                            const int*   __restrict__ rel_idx,
                            char* __restrict__ ws) {
    int idx = blockIdx.x * 256 + threadIdx.x;
    if (idx < 110592) {                       // wqkv_t / wqkvm_t: [ks][col][32]
        int col = idx / 192, k = idx - col * 192;
        float sc = (col < 192) ? SCALE_F * LOG2E_F : 1.0f;  // Q pre-scale (exp2)
        int dst = (k >> 5) * 18432 + col * 32 + (k & 31);
        ((__bf16*)(ws + WS_WQKV_T))[dst]  = (__bf16)(w_qkv[k * 576 + col] * sc);
        ((__bf16*)(ws + WS_WQKVM_T))[dst] = (__bf16)(w_qkvm[k * 576 + col] * sc);
    } else if (idx < 184320) {                // wproj_t: [n][k]
        int o = idx - 110592;
        int n = o / 384, k = o - n * 384;
        ((__bf16*)(ws + WS_WPROJ_T))[o] = (__bf16)w_proj[k * 192 + n];
    } else if (idx < 282624) {                // rpbg: [h][i][half*64 + l16*4 + j]
        int o = idx - 184320;
        int h = o / 16384, r2 = o - h * 16384;
        int i = r2 >> 7, c = r2 & 127;
        int half = c >> 6, cc = c & 63;
        int l16 = cc >> 2, jj = cc & 3;
        int jcol = l16 + (half * 4 + jj) * 16;    // original column index
        ((__bf16*)(ws + WS_RPBG))[o] =
            (__bf16)(rpb_table[rel_idx[i * 128 + jcol] * 6 + h] * LOG2E_F);
    }
}

// ---------------------------------------------------------------------------
// Block = (window, branch). 512 threads = 8 waves; wave w owns query rows
// [16w, 16w+16). MFMA 16x16x32 bf16 layouts (HW-verified):
//   A[m = lane&15][k = quad*8 + j]; B[k = quad*8 + j][n = lane&15]
//   D: col = lane&15, row = quad*4 + reg
// LDS (37,376 B -> 4 blocks/CU, 32 waves/CU):
//   kh1 [128][40]  @ 0      K for current head [token][dim]   (stride 80B)
//   vt1 [32][136]  @ 10240  V^T for current head [dim][token] (stride 272B)
//   qs  [8][16][72] @ 18944 wave-private Q / P / out staging  (stride 144B)
__global__ __launch_bounds__(512, 4)
void attn_kernel(const float* __restrict__ x,
                 const float* __restrict__ mask,
                 const float* __restrict__ pos_bias,
                 const char*  __restrict__ ws,
                 __bf16* __restrict__ concat) {
    __shared__ alignas(16) __bf16 kh1[128][40];
    __shared__ alignas(16) __bf16 vt1[32][136];
    __shared__ alignas(16) __bf16 qs[8][16][72];

    // XCD-bijective swizzle: HW maps blockIdx%8 -> XCD. Branch pairs of a
    // window run adjacently on one XCD; each XCD serves 8 mask windows
    // (8 x 64KB = 512KB, L2-resident).
    const int i0     = blockIdx.x;
    const int xcd    = i0 & 7;
    const int j0     = i0 >> 3;
    const int branch = j0 & 1;
    const int wm     = (j0 >> 5) * 8 + xcd;
    const int b      = ((j0 >> 1) & 15) * 64 + wm;

    const int tid  = threadIdx.x;
    const int wave = tid >> 6;
    const int lane = tid & 63;
    const int quad = lane >> 4;
    const int l16  = lane & 15;
    const int mrow = wave * 16;

    const __bf16* wt   = (const __bf16*)(ws + (branch ? WS_WQKVM_T : WS_WQKV_T));
    const __bf16* rpbg = (const __bf16*)(ws + WS_RPBG);
    __bf16 (*qw)[72] = qs[wave];

    // ---- x rows for this wave -> A-fragments in registers (reused 18x) ----
    bf16x8 afrag[6];
    {
        const float* xr = x + (size_t)b * 24576 + (mrow + l16) * 192;
        const float* pr = pos_bias + ((mrow + l16) & 63) * 192;
        #pragma unroll
        for (int ks = 0; ks < 6; ++ks) {
            const int k0 = ks * 32 + quad * 8;
            float4 v0 = *(const float4*)(xr + k0);
            float4 v1 = *(const float4*)(xr + k0 + 4);
            if (branch) {
                float4 p0 = *(const float4*)(pr + k0);
                float4 p1 = *(const float4*)(pr + k0 + 4);
                v0.x += p0.x; v0.y += p0.y; v0.z += p0.z; v0.w += p0.w;
                v1.x += p1.x; v1.y += p1.y; v1.z += p1.z; v1.w += p1.w;
            }
            bf16x8 f;
            f[0] = (__bf16)v0.x; f[1] = (__bf16)v0.y;
            f[2] = (__bf16)v0.z; f[3] = (__bf16)v0.w;
            f[4] = (__bf16)v1.x; f[5] = (__bf16)v1.y;
            f[6] = (__bf16)v1.z; f[7] = (__bf16)v1.w;
            afrag[ks] = f;
        }
    }

    // 2-wide proj with double-buffered, fully-coalesced weight loads.
    // Weight layout [ks][col][32]: lanes of a wave read 1KB contiguous.
    auto runproj2 = [&](int rowbase, f32x4* acc) {
        const __bf16* wb = wt + (size_t)(rowbase + l16) * 32 + quad * 8;
        bf16x8 bA0 = *(const bf16x8*)(wb);
        bf16x8 bA1 = *(const bf16x8*)(wb + 512);
        bf16x8 bB0, bB1;
        #pragma unroll
        for (int ks = 0; ks < 6; ++ks) {
            const __bf16* wn = wb + (size_t)(ks + 1) * 18432;
            if ((ks & 1) == 0) {
                if (ks < 5) { bB0 = *(const bf16x8*)(wn);
                              bB1 = *(const bf16x8*)(wn + 512); }
                acc[0] = MFMA(afrag[ks], bA0, acc[0]);
                acc[1] = MFMA(afrag[ks], bA1, acc[1]);
            } else {
                if (ks < 5) { bA0 = *(const bf16x8*)(wn);
                              bA1 = *(const bf16x8*)(wn + 512); }
                acc[0] = MFMA(afrag[ks], bB0, acc[0]);
                acc[1] = MFMA(afrag[ks], bB1, acc[1]);
            }
        }
    };

    #pragma unroll 1
    for (int h = 0; h < 6; ++h) {
        // ---- K -> kh1 [token][dim] ----
        {
            f32x4 acc[2] = {};
            runproj2(192 + h * 32, acc);
            #pragma unroll
            for (int nt = 0; nt < 2; ++nt)
                #pragma unroll
                for (int r = 0; r < 4; ++r)
                    kh1[mrow + quad * 4 + r][nt * 16 + l16] = (__bf16)acc[nt][r];
        }
        // ---- V -> vt1 [dim][token] ----
        {
            f32x4 acc[2] = {};
            runproj2(384 + h * 32, acc);
            #pragma unroll
            for (int nt = 0; nt < 2; ++nt) {
                bf16x4 pv;
                #pragma unroll
                for (int r = 0; r < 4; ++r) pv[r] = (__bf16)acc[nt][r];
                *(bf16x4*)&vt1[nt * 16 + l16][mrow + quad * 4] = pv;
            }
        }
        // ---- Q (pre-scaled) -> qw -> A-fragment ----
        bf16x8 aq;
        {
            f32x4 acc[2] = {};
            runproj2(h * 32, acc);
            #pragma unroll
            for (int nt = 0; nt < 2; ++nt)
                #pragma unroll
                for (int r = 0; r < 4; ++r)
                    qw[quad * 4 + r][nt * 16 + l16] = (__bf16)acc[nt][r];
            aq = *(const bf16x8*)&qw[l16][quad * 8];
        }
        __syncthreads();    // (A) K/V visible to all waves

        f32x4 o0 = {}, o1 = {};
        float rsum[4] = {0.f, 0.f, 0.f, 0.f};

        if (branch == 0) {
            const float*  mp = mask + ((size_t)wm * 128 + mrow + quad * 4) * 128 + l16;
            const __bf16* rb = rpbg + ((size_t)(h * 128 + mrow + quad * 4) << 7) + l16 * 4;
            #pragma unroll
            for (int half = 0; half < 2; ++half) {
                f32x4 s4[4];
                // C-init = mask*log2e + rpb (both in exp2 domain)
                #pragma unroll
                for (int r = 0; r < 4; ++r) {
                    bf16x4 rvr = *(const bf16x4*)(rb + r * 128 + half * 64);
                    #pragma unroll
                    for (int j = 0; j < 4; ++j)
                        s4[j][r] = fmaf(mp[r * 128 + (half * 4 + j) * 16],
                                        LOG2E_F, (float)rvr[j]);
                }
                #pragma unroll
                for (int j = 0; j < 4; ++j) {
                    bf16x8 bk = *(const bf16x8*)
                        &kh1[(half * 4 + j) * 16 + l16][quad * 8];
                    s4[j] = MFMA(aq, bk, s4[j]);
                }
                #pragma unroll
                for (int r = 0; r < 4; ++r)
                    #pragma unroll
                    for (int j = 0; j < 4; ++j) {
                        float p = EXP2(s4[j][r]);
                        s4[j][r] = p;
                        rsum[r] += p;
                    }
                #pragma unroll
                for (int j = 0; j < 4; ++j)
                    #pragma unroll
                    for (int r = 0; r < 4; ++r)
                        qw[quad * 4 + r][j * 16 + l16] = (__bf16)s4[j][r];
                #pragma unroll
                for (int kb = 0; kb < 2; ++kb) {
                    bf16x8 p = *(const bf16x8*)&qw[l16][kb * 32 + quad * 8];
                    bf16x8 bv0 = *(const bf16x8*)
                        &vt1[l16][half * 64 + kb * 32 + quad * 8];
                    bf16x8 bv1 = *(const bf16x8*)
                        &vt1[16 + l16][half * 64 + kb * 32 + quad * 8];
                    o0 = MFMA(p, bv0, o0);
                    o1 = MFMA(p, bv1, o1);
                }
            }
        } else {
            const int kbase = (mrow < 64) ? 64 : 0;
            const float* mp = mask
                + ((size_t)wm * 128 + ((mrow + quad * 4) & 63)) * 128 + l16;
            f32x4 s4[4];
            #pragma unroll
            for (int r = 0; r < 4; ++r)
                #pragma unroll
                for (int j = 0; j < 4; ++j)
                    s4[j][r] = mp[r * 128 + j * 16] * LOG2E_F;
            #pragma unroll
            for (int j = 0; j < 4; ++j) {
                bf16x8 bk = *(const bf16x8*)
                    &kh1[kbase + j * 16 + l16][quad * 8];
                s4[j] = MFMA(aq, bk, s4[j]);
            }
            #pragma unroll
            for (int r = 0; r < 4; ++r)
                #pragma unroll
                for (int j = 0; j < 4; ++j) {
                    float p = EXP2(s4[j][r]);
                    s4[j][r] = p;
                    rsum[r] += p;
                }
            #pragma unroll
            for (int j = 0; j < 4; ++j)
                #pragma unroll
                for (int r = 0; r < 4; ++r)
                    qw[quad * 4 + r][j * 16 + l16] = (__bf16)s4[j][r];
            #pragma unroll
            for (int kb = 0; kb < 2; ++kb) {
                bf16x8 p = *(const bf16x8*)&qw[l16][kb * 32 + quad * 8];
                bf16x8 bv0 = *(const bf16x8*)
                    &vt1[l16][kbase + kb * 32 + quad * 8];
                bf16x8 bv1 = *(const bf16x8*)
                    &vt1[16 + l16][kbase + kb * 32 + quad * 8];
                o0 = MFMA(p, bv0, o0);
                o1 = MFMA(p, bv1, o1);
            }
        }

        float rl[4];
        #pragma unroll
        for (int r = 0; r < 4; ++r) {
            float sum = rsum[r];
            #pragma unroll
            for (int off = 1; off < 16; off <<= 1)
                sum += __shfl_xor(sum, off, 64);
            rl[r] = RCP(sum);
        }
        __syncthreads();    // (B) all kh1/vt1 reads done -> next head may write

        // ---- per-head output: wave-private 16x32 LDS transpose -> uint4 ----
        #pragma unroll
        for (int r = 0; r < 4; ++r) {
            qw[quad * 4 + r][l16]      = (__bf16)(o0[r] * rl[r]);
            qw[quad * 4 + r][16 + l16] = (__bf16)(o1[r] * rl[r]);
        }
        {
            const int rloc = lane >> 2;
            const int cpart = (lane & 3) * 8;
            uint4 val = *(const uint4*)&qw[rloc][cpart];
            const int grow = mrow + rloc;
            const int rowm = branch ? ((grow + 64) & 127) : grow;
            const int colofs = branch ? 0 : 192;
            *(uint4*)&concat[((size_t)b * 128 + rowm) * 384 + colofs + h * 32 + cpart] = val;
        }
    }
}

// ---------------------------------------------------------------------------
// out = concat @ w_proj + b_proj. 64 rows/block, 256 thr (4 waves x 16 rows),
// weights staged in four 96-K chunks (38.4 KB LDS -> 4 blocks/CU). A-frags
// hoisted before first barrier. concat aliases d_out: rows block-exclusive,
// reads complete (in-wave) before epilogue stores.
__global__ __launch_bounds__(256, 4)
void proj_kernel(const __bf16* __restrict__ concat,
                 const char* __restrict__ ws,
                 const float* __restrict__ b_proj,
                 float* __restrict__ out) {
    __shared__ alignas(16) __bf16 bw[192][100];
    const __bf16* wp = (const __bf16*)(ws + WS_WPROJ_T);
    const int tid  = threadIdx.x;
    const int wave = tid >> 6;
    const int lane = tid & 63;
    const int quad = lane >> 4;
    const int l16  = lane & 15;
    const int mrow = wave * 16;
    const size_t r0 = (size_t)blockIdx.x * 64;

    bf16x8 a[12];
    {
        const __bf16* arow = concat + (r0 + mrow + l16) * 384;
        #pragma unroll
        for (int ks = 0; ks < 12; ++ks)
            a[ks] = *(const bf16x8*)&arow[ks * 32 + quad * 8];
    }
    f32x4 acc[12] = {};
    for (int c = 0; c < 4; ++c) {
        if (c) __syncthreads();
        #pragma unroll
        for (int i = 0; i < 9; ++i) {
            int f = tid + i * 256;            // 0..2303 (192 rows x 12 uint4)
            int row = f / 12;
            int cc = (f - row * 12) * 8;
            *(uint4*)&bw[row][cc] = *(const uint4*)&wp[row * 384 + c * 96 + cc];
        }
        __syncthreads();
        #pragma unroll
        for (int k3 = 0; k3 < 3; ++k3) {
            const int k0 = k3 * 32 + quad * 8;
            bf16x8 af = a[c * 3 + k3];
            #pragma unroll
            for (int nt = 0; nt < 12; ++nt) {
                bf16x8 bb = *(const bf16x8*)&bw[nt * 16 + l16][k0];
                acc[nt] = MFMA(af, bb, acc[nt]);
            }
        }
    }
    #pragma unroll
    for (int nt = 0; nt < 12; ++nt) {
        const int cc = nt * 16 + l16;
        const float bias = b_proj[cc];
        #pragma unroll
        for (int r = 0; r < 4; ++r)
            out[(r0 + mrow + quad * 4 + r) * 192 + cc] = acc[nt][r] + bias;
    }
}

// ---------------------------------------------------------------------------
extern "C" void kernel_launch(void* const* d_in, const int* in_sizes, int n_in,
                              void* d_out, int out_size, void* d_ws, size_t ws_size,
                              hipStream_t stream) {
    const float* x       = (const float*)d_in[0];
    const float* mask    = (const float*)d_in[1];
    const float* w_qkv   = (const float*)d_in[2];
    const float* w_qkvm  = (const float*)d_in[3];
    const float* w_proj  = (const float*)d_in[4];
    const float* b_proj  = (const float*)d_in[5];
    const float* rpb     = (const float*)d_in[6];
    const float* pos_b   = (const float*)d_in[7];
    const int*   rel_idx = (const int*)d_in[8];

    if (ws_size < WS_NEEDED) return;

    char*   ws     = (char*)d_ws;
    __bf16* concat = (__bf16*)d_out;   // 131072*384 bf16 == out bytes, exact fit
    float*  out    = (float*)d_out;

    prep_kernel<<<1104, 256, 0, stream>>>(w_qkv, w_qkvm, w_proj, rpb, rel_idx, ws);
    attn_kernel<<<2048, 512, 0, stream>>>(x, mask, pos_b, ws, concat);
    proj_kernel<<<2048, 256, 0, stream>>>(concat, ws, b_proj, out);
}

// Round 3
// 395.535 us; speedup vs baseline: 1.9145x; 1.2873x over previous
//
#include <hip/hip_runtime.h>
#include <hip/hip_bf16.h>
#include <math.h>

// ---------------------------------------------------------------------------
// WindowAttention (self + mutual), MI355X / gfx950.
// R7: async-staging attack. Occupancy is reg-capped at 2 blocks/CU (R6 showed
// 41% occupancy at both 79KB and 37KB LDS), so LDS to ~80KB is free. Per-head
// weights (36KB) now cooperatively staged into LDS via global_load_lds with
// cross-head prefetch (issued after barrier A, drained at barrier B, hidden
// under the attention phase): proj phase has ZERO global loads. Slot-swizzle
// involution (s ^= (s>>3)&7 on 16B slots) pre-applied on the global source
// (LDS dest must be linear) and re-applied on ds_read => bank-optimal b128.
// proj_kernel rebuilt: 128 rows/block, 1024 blocks, 2-phase double-buffered
// global_load_lds chunk pipeline (stage c+1 under compute c).
// ---------------------------------------------------------------------------

#define SCALE_F 0.17677669529663687f   // 32^-0.5
#define LOG2E_F 1.4426950408889634f

// ws layout (bytes)
#define WS_WQKV_T   0u        // [6 ks][576 col][32 k] bf16 (Q-cols ×SCALE×LOG2E)
#define WS_WQKVM_T  221184u   // [6 ks][576 col][32 k] bf16
#define WS_WPROJ_T  442368u   // [192 n][384 k] bf16
#define WS_RPBG     589824u   // [6][128][half*64 + l16*4 + j] bf16, ×LOG2E
#define WS_NEEDED   786432u

typedef __bf16 bf16x8 __attribute__((ext_vector_type(8)));
typedef __bf16 bf16x4 __attribute__((ext_vector_type(4)));
typedef float  f32x4  __attribute__((ext_vector_type(4)));

#define MFMA(a, b, c) __builtin_amdgcn_mfma_f32_16x16x32_bf16((a), (b), (c), 0, 0, 0)

#if __has_builtin(__builtin_amdgcn_exp2f)
#define EXP2(x) __builtin_amdgcn_exp2f(x)
#else
#define EXP2(x) exp2f(x)
#endif
#if __has_builtin(__builtin_amdgcn_rcpf)
#define RCP(x) __builtin_amdgcn_rcpf(x)
#else
#define RCP(x) (1.0f / (x))
#endif

// direct global -> LDS DMA, 16B per lane; LDS dest is wave-uniform base +
// lane*16 (linear), global source is per-lane (pre-swizzled by caller).
#define GLOAD_LDS(gp, lp)                                                   \
    __builtin_amdgcn_global_load_lds(                                       \
        (const __attribute__((address_space(1))) unsigned int*)(gp),        \
        (__attribute__((address_space(3))) unsigned int*)(lp), 16, 0, 0)

// ---------------------------------------------------------------------------
__global__ void prep_kernel(const float* __restrict__ w_qkv,
                            const float* __restrict__ w_qkvm,
                            const float* __restrict__ w_proj,
                            const float* __restrict__ rpb_table,
                            const int*   __restrict__ rel_idx,
                            char* __restrict__ ws) {
    int idx = blockIdx.x * 256 + threadIdx.x;
    if (idx < 110592) {                       // wqkv_t / wqkvm_t: [ks][col][32]
        int col = idx / 192, k = idx - col * 192;
        float sc = (col < 192) ? SCALE_F * LOG2E_F : 1.0f;  // Q pre-scale (exp2)
        int dst = (k >> 5) * 18432 + col * 32 + (k & 31);
        ((__bf16*)(ws + WS_WQKV_T))[dst]  = (__bf16)(w_qkv[k * 576 + col] * sc);
        ((__bf16*)(ws + WS_WQKVM_T))[dst] = (__bf16)(w_qkvm[k * 576 + col] * sc);
    } else if (idx < 184320) {                // wproj_t: [n][k]
        int o = idx - 110592;
        int n = o / 384, k = o - n * 384;
        ((__bf16*)(ws + WS_WPROJ_T))[o] = (__bf16)w_proj[k * 192 + n];
    } else if (idx < 282624) {                // rpbg: [h][i][half*64 + l16*4 + j]
        int o = idx - 184320;
        int h = o / 16384, r2 = o - h * 16384;
        int i = r2 >> 7, c = r2 & 127;
        int half = c >> 6, cc = c & 63;
        int l16 = cc >> 2, jj = cc & 3;
        int jcol = l16 + (half * 4 + jj) * 16;    // original column index
        ((__bf16*)(ws + WS_RPBG))[o] =
            (__bf16)(rpb_table[rel_idx[i * 128 + jcol] * 6 + h] * LOG2E_F);
    }
}

// ---------------------------------------------------------------------------
// Block = (window, branch). 512 threads = 8 waves; wave w owns query rows
// [16w, 16w+16). MFMA 16x16x32 bf16 layouts (HW-verified):
//   A[m = lane&15][k = quad*8 + j]; B[k = quad*8 + j][n = lane&15]
//   D: col = lane&15, row = quad*4 + reg
// LDS (74,240 B -> 2 blocks/CU; reg-capped at 2 blocks anyway):
//   wbuf [18432]   @ -      per-head Q/K/V weights, 36 x 1KB chunks,
//                           chunk (p,ks,half) = ((p*6+ks)*2+half)*512 el,
//                           16B slots stored swizzled: phys = s ^ ((s>>3)&7)
//   kh1 [128][40]           K for current head [token][dim]
//   vt1 [32][136]           V^T for current head [dim][token]
//   qs  [8][16][72]         wave-private Q / P / out staging
__global__ __launch_bounds__(512, 4)
void attn_kernel(const float* __restrict__ x,
                 const float* __restrict__ mask,
                 const float* __restrict__ pos_bias,
                 const char*  __restrict__ ws,
                 __bf16* __restrict__ concat) {
    __shared__ alignas(16) __bf16 wbuf[18432];
    __shared__ alignas(16) __bf16 kh1[128][40];
    __shared__ alignas(16) __bf16 vt1[32][136];
    __shared__ alignas(16) __bf16 qs[8][16][72];

    // XCD-bijective swizzle: branch pairs adjacent on one XCD; 8 mask windows
    // per XCD (512KB, L2-resident).
    const int i0     = blockIdx.x;
    const int xcd    = i0 & 7;
    const int j0     = i0 >> 3;
    const int branch = j0 & 1;
    const int wm     = (j0 >> 5) * 8 + xcd;
    const int b      = ((j0 >> 1) & 15) * 64 + wm;

    const int tid  = threadIdx.x;
    const int wave = tid >> 6;
    const int lane = tid & 63;
    const int quad = lane >> 4;
    const int l16  = lane & 15;
    const int mrow = wave * 16;

    const __bf16* wt   = (const __bf16*)(ws + (branch ? WS_WQKVM_T : WS_WQKV_T));
    const __bf16* rpbg = (const __bf16*)(ws + WS_RPBG);
    __bf16 (*qw)[72] = qs[wave];

    // swizzled slot offsets (elements): stage source & proj ds_read side
    const int sl8 = (lane ^ ((lane >> 3) & 7)) * 8;            // stage side
    const int spq = (l16 * 4 + quad);
    const int sp8 = (spq ^ ((spq >> 3) & 7)) * 8;              // read side

    // ---- stage head h weights (36KB, 36 x 1KB wave-chunks) into wbuf ----
    auto stage = [&](int h) {
        #pragma unroll
        for (int ii = 0; ii < 5; ++ii) {
            const int i = wave + ii * 8;
            if (i < 36) {
                const int p = i / 12, r = i - p * 12;
                const int ks = r >> 1, half = r & 1;
                const __bf16* gp = wt + ks * 18432
                    + (p * 192 + h * 32 + half * 16) * 32 + sl8;
                GLOAD_LDS(gp, &wbuf[i * 512]);
            }
        }
    };

    // ---- x rows for this wave -> A-fragments in registers (reused 18x) ----
    bf16x8 afrag[6];
    {
        const float* xr = x + (size_t)b * 24576 + (mrow + l16) * 192;
        const float* pr = pos_bias + ((mrow + l16) & 63) * 192;
        #pragma unroll
        for (int ks = 0; ks < 6; ++ks) {
            const int k0 = ks * 32 + quad * 8;
            float4 v0 = *(const float4*)(xr + k0);
            float4 v1 = *(const float4*)(xr + k0 + 4);
            if (branch) {
                float4 p0 = *(const float4*)(pr + k0);
                float4 p1 = *(const float4*)(pr + k0 + 4);
                v0.x += p0.x; v0.y += p0.y; v0.z += p0.z; v0.w += p0.w;
                v1.x += p1.x; v1.y += p1.y; v1.z += p1.z; v1.w += p1.w;
            }
            bf16x8 f;
            f[0] = (__bf16)v0.x; f[1] = (__bf16)v0.y;
            f[2] = (__bf16)v0.z; f[3] = (__bf16)v0.w;
            f[4] = (__bf16)v1.x; f[5] = (__bf16)v1.y;
            f[6] = (__bf16)v1.z; f[7] = (__bf16)v1.w;
            afrag[ks] = f;
        }
    }

    // proj from LDS weights: acc[0..1] += x @ W^T  (p: 0=Q, 1=K, 2=V)
    auto runproj2 = [&](int p, f32x4* acc) {
        const int cb = p * 6144;
        #pragma unroll
        for (int ks = 0; ks < 6; ++ks) {
            bf16x8 b0 = *(const bf16x8*)&wbuf[cb + ks * 1024 + sp8];
            bf16x8 b1 = *(const bf16x8*)&wbuf[cb + ks * 1024 + 512 + sp8];
            acc[0] = MFMA(afrag[ks], b0, acc[0]);
            acc[1] = MFMA(afrag[ks], b1, acc[1]);
        }
    };

    stage(0);
    __syncthreads();    // staging drained (compiler emits vmcnt(0) at barrier)

    #pragma unroll 1
    for (int h = 0; h < 6; ++h) {
        // ---- K -> kh1 [token][dim] ----
        {
            f32x4 acc[2] = {};
            runproj2(1, acc);
            #pragma unroll
            for (int nt = 0; nt < 2; ++nt)
                #pragma unroll
                for (int r = 0; r < 4; ++r)
                    kh1[mrow + quad * 4 + r][nt * 16 + l16] = (__bf16)acc[nt][r];
        }
        // ---- V -> vt1 [dim][token] ----
        {
            f32x4 acc[2] = {};
            runproj2(2, acc);
            #pragma unroll
            for (int nt = 0; nt < 2; ++nt) {
                bf16x4 pv;
                #pragma unroll
                for (int r = 0; r < 4; ++r) pv[r] = (__bf16)acc[nt][r];
                *(bf16x4*)&vt1[nt * 16 + l16][mrow + quad * 4] = pv;
            }
        }
        // ---- Q (pre-scaled) -> qw -> A-fragment ----
        bf16x8 aq;
        {
            f32x4 acc[2] = {};
            runproj2(0, acc);
            #pragma unroll
            for (int nt = 0; nt < 2; ++nt)
                #pragma unroll
                for (int r = 0; r < 4; ++r)
                    qw[quad * 4 + r][nt * 16 + l16] = (__bf16)acc[nt][r];
            aq = *(const bf16x8*)&qw[l16][quad * 8];
        }
        __syncthreads();    // (A) K/V visible; all wbuf reads of head h done

        if (h < 5) stage(h + 1);   // prefetch next head under attention phase

        f32x4 o0 = {}, o1 = {};
        float rsum[4] = {0.f, 0.f, 0.f, 0.f};

        if (branch == 0) {
            const float*  mp = mask + ((size_t)wm * 128 + mrow + quad * 4) * 128 + l16;
            const __bf16* rb = rpbg + ((size_t)(h * 128 + mrow + quad * 4) << 7) + l16 * 4;
            #pragma unroll
            for (int half = 0; half < 2; ++half) {
                f32x4 s4[4];
                // C-init = mask*log2e + rpb (both in exp2 domain)
                #pragma unroll
                for (int r = 0; r < 4; ++r) {
                    bf16x4 rvr = *(const bf16x4*)(rb + r * 128 + half * 64);
                    #pragma unroll
                    for (int j = 0; j < 4; ++j)
                        s4[j][r] = fmaf(mp[r * 128 + (half * 4 + j) * 16],
                                        LOG2E_F, (float)rvr[j]);
                }
                #pragma unroll
                for (int j = 0; j < 4; ++j) {
                    bf16x8 bk = *(const bf16x8*)
                        &kh1[(half * 4 + j) * 16 + l16][quad * 8];
                    s4[j] = MFMA(aq, bk, s4[j]);
                }
                #pragma unroll
                for (int r = 0; r < 4; ++r)
                    #pragma unroll
                    for (int j = 0; j < 4; ++j) {
                        float p = EXP2(s4[j][r]);
                        s4[j][r] = p;
                        rsum[r] += p;
                    }
                #pragma unroll
                for (int j = 0; j < 4; ++j)
                    #pragma unroll
                    for (int r = 0; r < 4; ++r)
                        qw[quad * 4 + r][j * 16 + l16] = (__bf16)s4[j][r];
                #pragma unroll
                for (int kb = 0; kb < 2; ++kb) {
                    bf16x8 p = *(const bf16x8*)&qw[l16][kb * 32 + quad * 8];
                    bf16x8 bv0 = *(const bf16x8*)
                        &vt1[l16][half * 64 + kb * 32 + quad * 8];
                    bf16x8 bv1 = *(const bf16x8*)
                        &vt1[16 + l16][half * 64 + kb * 32 + quad * 8];
                    o0 = MFMA(p, bv0, o0);
                    o1 = MFMA(p, bv1, o1);
                }
            }
        } else {
            const int kbase = (mrow < 64) ? 64 : 0;
            const float* mp = mask
                + ((size_t)wm * 128 + ((mrow + quad * 4) & 63)) * 128 + l16;
            f32x4 s4[4];
            #pragma unroll
            for (int r = 0; r < 4; ++r)
                #pragma unroll
                for (int j = 0; j < 4; ++j)
                    s4[j][r] = mp[r * 128 + j * 16] * LOG2E_F;
            #pragma unroll
            for (int j = 0; j < 4; ++j) {
                bf16x8 bk = *(const bf16x8*)
                    &kh1[kbase + j * 16 + l16][quad * 8];
                s4[j] = MFMA(aq, bk, s4[j]);
            }
            #pragma unroll
            for (int r = 0; r < 4; ++r)
                #pragma unroll
                for (int j = 0; j < 4; ++j) {
                    float p = EXP2(s4[j][r]);
                    s4[j][r] = p;
                    rsum[r] += p;
                }
            #pragma unroll
            for (int j = 0; j < 4; ++j)
                #pragma unroll
                for (int r = 0; r < 4; ++r)
                    qw[quad * 4 + r][j * 16 + l16] = (__bf16)s4[j][r];
            #pragma unroll
            for (int kb = 0; kb < 2; ++kb) {
                bf16x8 p = *(const bf16x8*)&qw[l16][kb * 32 + quad * 8];
                bf16x8 bv0 = *(const bf16x8*)
                    &vt1[l16][kbase + kb * 32 + quad * 8];
                bf16x8 bv1 = *(const bf16x8*)
                    &vt1[16 + l16][kbase + kb * 32 + quad * 8];
                o0 = MFMA(p, bv0, o0);
                o1 = MFMA(p, bv1, o1);
            }
        }

        float rl[4];
        #pragma unroll
        for (int r = 0; r < 4; ++r) {
            float sum = rsum[r];
            #pragma unroll
            for (int off = 1; off < 16; off <<= 1)
                sum += __shfl_xor(sum, off, 64);
            rl[r] = RCP(sum);
        }
        __syncthreads();    // (B) kh1/vt1 reads done; prefetch drained here

        // ---- per-head output: wave-private 16x32 LDS transpose -> uint4 ----
        #pragma unroll
        for (int r = 0; r < 4; ++r) {
            qw[quad * 4 + r][l16]      = (__bf16)(o0[r] * rl[r]);
            qw[quad * 4 + r][16 + l16] = (__bf16)(o1[r] * rl[r]);
        }
        {
            const int rloc = lane >> 2;
            const int cpart = (lane & 3) * 8;
            uint4 val = *(const uint4*)&qw[rloc][cpart];
            const int grow = mrow + rloc;
            const int rowm = branch ? ((grow + 64) & 127) : grow;
            const int colofs = branch ? 0 : 192;
            *(uint4*)&concat[((size_t)b * 128 + rowm) * 384 + colofs + h * 32 + cpart] = val;
        }
    }
}

// ---------------------------------------------------------------------------
// out = concat @ w_proj + b_proj. 128 rows/block, 512 thr (8 waves x 16 rows),
// 1024 blocks. Weights in four 96-K chunks, double-buffered via
// global_load_lds (stage c+1 under compute c), slot-swizzled for bank-optimal
// ds_read_b128. concat aliases d_out: rows block-exclusive, all reads precede
// stores in program order.
__global__ __launch_bounds__(512, 4)
void proj_kernel(const __bf16* __restrict__ concat,
                 const char* __restrict__ ws,
                 const float* __restrict__ b_proj,
                 float* __restrict__ out) {
    __shared__ alignas(16) __bf16 bwA[18432];   // [192 n][96 k] chunk, swizzled slots
    __shared__ alignas(16) __bf16 bwB[18432];
    const __bf16* wp = (const __bf16*)(ws + WS_WPROJ_T);
    const int tid  = threadIdx.x;
    const int wave = tid >> 6;
    const int lane = tid & 63;
    const int quad = lane >> 4;
    const int l16  = lane & 15;
    const int mrow = wave * 16;
    const size_t r0 = (size_t)blockIdx.x * 128;

    const int sl8 = (lane ^ ((lane >> 3) & 7)) * 8;   // stage-side swizzle

    // ---- A-fragments (concat rows) issued first, in flight during stage ----
    bf16x8 a[12];
    {
        const __bf16* arow = concat + (r0 + mrow + l16) * 384;
        #pragma unroll
        for (int ks = 0; ks < 12; ++ks)
            a[ks] = *(const bf16x8*)&arow[ks * 32 + quad * 8];
    }

    auto stageP = [&](int c, __bf16* buf) {
        #pragma unroll
        for (int ii = 0; ii < 5; ++ii) {
            const int i = wave + ii * 8;
            if (i < 36) {
                const int e = i * 512 + sl8;          // logical element
                const int row = e / 96;
                const int col = e - row * 96;
                const __bf16* gp = wp + row * 384 + c * 96 + col;
                GLOAD_LDS(gp, &buf[i * 512]);
            }
        }
    };

    f32x4 acc[12] = {};
    auto computeC = [&](const __bf16* buf, int c) {
        #pragma unroll
        for (int k3 = 0; k3 < 3; ++k3) {
            bf16x8 af = a[c * 3 + k3];
            #pragma unroll
            for (int nt = 0; nt < 12; ++nt) {
                const int s  = l16 * 12 + quad + nt * 192 + k3 * 4;
                const int sp = s ^ ((s >> 3) & 7);
                bf16x8 bb = *(const bf16x8*)&buf[sp * 8];
                acc[nt] = MFMA(af, bb, acc[nt]);
            }
        }
    };

    stageP(0, bwA);
    __syncthreads();          // bwA ready (+ a[] drained)
    stageP(1, bwB);
    computeC(bwA, 0);
    __syncthreads();          // bwB ready; bwA free
    stageP(2, bwA);
    computeC(bwB, 1);
    __syncthreads();          // bwA ready; bwB free
    stageP(3, bwB);
    computeC(bwA, 2);
    __syncthreads();          // bwB ready
    computeC(bwB, 3);

    #pragma unroll
    for (int nt = 0; nt < 12; ++nt) {
        const int cc = nt * 16 + l16;
        const float bias = b_proj[cc];
        #pragma unroll
        for (int r = 0; r < 4; ++r)
            out[(r0 + mrow + quad * 4 + r) * 192 + cc] = acc[nt][r] + bias;
    }
}

// ---------------------------------------------------------------------------
extern "C" void kernel_launch(void* const* d_in, const int* in_sizes, int n_in,
                              void* d_out, int out_size, void* d_ws, size_t ws_size,
                              hipStream_t stream) {
    const float* x       = (const float*)d_in[0];
    const float* mask    = (const float*)d_in[1];
    const float* w_qkv   = (const float*)d_in[2];
    const float* w_qkvm  = (const float*)d_in[3];
    const float* w_proj  = (const float*)d_in[4];
    const float* b_proj  = (const float*)d_in[5];
    const float* rpb     = (const float*)d_in[6];
    const float* pos_b   = (const float*)d_in[7];
    const int*   rel_idx = (const int*)d_in[8];

    if (ws_size < WS_NEEDED) return;

    char*   ws     = (char*)d_ws;
    __bf16* concat = (__bf16*)d_out;   // 131072*384 bf16 == out bytes, exact fit
    float*  out    = (float*)d_out;

    prep_kernel<<<1104, 256, 0, stream>>>(w_qkv, w_qkvm, w_proj, rpb, rel_idx, ws);
    attn_kernel<<<2048, 512, 0, stream>>>(x, mask, pos_b, ws, concat);
    proj_kernel<<<1024, 512, 0, stream>>>(concat, ws, b_proj, out);
}